// Round 15
// baseline (543.179 us; speedup 1.0000x reference)
//
#include <hip/hip_runtime.h>
#include <hip/hip_bf16.h>
#include <math.h>

// MoE MLP, MI355X. B=2,S=2048 -> NTOK=4096 tokens, D=1024, F=4096, E=8, top2.
#define NTOK 4096
#define DD 1024
#define FF 4096
#define NEXP 8
#define EBM 128          // tile M
#define EBN 128          // tile N
#define EBK 32           // K-step -> 33.8KB LDS -> 4 blocks/CU (r10 measured optimum)
#define PAIR_CAP 9216    // 8192 pairs + 8*127 pad, rounded to 128
#define TILES_MAX 72     // PAIR_CAP / 128

typedef short bf16x8 __attribute__((ext_vector_type(8)));
typedef float f32x4 __attribute__((ext_vector_type(4)));
typedef unsigned short u16x8 __attribute__((ext_vector_type(8)));

__device__ __forceinline__ ushort f2bf(float x) {
  unsigned u = __float_as_uint(x);
  unsigned r = (u + 0x7FFFu + ((u >> 16) & 1u)) >> 16;
  return (ushort)r;
}

__device__ __forceinline__ void async16(const void* g, void* l) {
  __builtin_amdgcn_global_load_lds(
      (const __attribute__((address_space(1))) char*)g,
      (__attribute__((address_space(3))) char*)l, 16, 0, 0);
}

// ---------------- small kernels ----------------

__global__ void k_convert4(const float4* __restrict__ s, ushort* __restrict__ d, int n4) {
  int i = blockIdx.x * 256 + threadIdx.x;
  if (i >= n4) return;
  float4 v = s[i];
  ushort4 o;
  o.x = f2bf(v.x); o.y = f2bf(v.y); o.z = f2bf(v.z); o.w = f2bf(v.w);
  *(ushort4*)(d + (size_t)i * 4) = o;
}

// src [E][R][C] f32 -> dst [E][C][R] bf16. 128r x 64c tiles; float4 reads,
// 256B-contiguous ushort8 write runs.
__global__ void k_transpose(const float* __restrict__ src, ushort* __restrict__ dst,
                            int R, int C) {
  __shared__ float tile[128][65];
  int e = blockIdx.z;
  const float* s = src + (size_t)e * R * C;
  ushort* d = dst + (size_t)e * R * C;
  int c0 = blockIdx.x * 64, r0 = blockIdx.y * 128;
  int tid = threadIdx.x;               // 256
  int rr0 = tid >> 4;                  // 0..15
  int cc4 = (tid & 15) * 4;            // 0..60
#pragma unroll
  for (int ps = 0; ps < 8; ++ps) {
    int r = ps * 16 + rr0;
    float4 v = *(const float4*)&s[(size_t)(r0 + r) * C + c0 + cc4];
    tile[r][cc4 + 0] = v.x; tile[r][cc4 + 1] = v.y;
    tile[r][cc4 + 2] = v.z; tile[r][cc4 + 3] = v.w;
  }
  __syncthreads();
  int cw = tid >> 4;                   // 0..15
  int rp = (tid & 15) * 8;             // 0..120
#pragma unroll
  for (int pass = 0; pass < 4; ++pass) {
    int c = pass * 16 + cw;
    u16x8 o;
#pragma unroll
    for (int k = 0; k < 8; ++k) o[k] = f2bf(tile[rp + k][c]);
    *(u16x8*)&d[(size_t)(c0 + c) * R + r0 + rp] = o;
  }
}

// u_part[kc][e][d] = (sum_{o in kc-chunk} Wp[o][d]*sim[e][o]) / max(||sim_e||,eps)
__global__ void k_u(const float* __restrict__ wp, const float* __restrict__ sim,
                    double* __restrict__ u_part) {
  __shared__ double sred[256];
  int tid = threadIdx.x;
  int dblk = blockIdx.x, e = blockIdx.y, kc = blockIdx.z;
  double s = 0.0;
#pragma unroll
  for (int j = 0; j < 4; ++j) {
    double v = sim[e * DD + j * 256 + tid];
    s += v * v;
  }
  sred[tid] = s;
  __syncthreads();
  for (int m = 128; m; m >>= 1) {
    if (tid < m) sred[tid] += sred[tid + m];
    __syncthreads();
  }
  double sn = fmax(sqrt(sred[0]), 1e-12);
  int d = dblk * 256 + tid;
  int o0 = kc * 256;
  double acc = 0.0;
#pragma unroll 8
  for (int o = o0; o < o0 + 256; ++o)
    acc += (double)wp[(size_t)o * DD + d] * (double)sim[e * DD + o];
  u_part[((size_t)kc * NEXP + e) * DD + d] = acc / sn;
}

// u = sum of 4 k-partials (deterministic)
__global__ void k_ured(const double* __restrict__ up, double* __restrict__ u) {
  int i = blockIdx.x * 256 + threadIdx.x;   // 8192
  u[i] = (up[i] + up[8192 + i]) + (up[16384 + i] + up[24576 + i]);
}

// per-token: n_e = x . u_e (f64); nu from nu_part inline; top2 + softmax
__global__ void k_gate(const float* __restrict__ x, const double* __restrict__ u,
                       const float* __restrict__ nu_part, const float* __restrict__ temp,
                       int* __restrict__ t2e, float* __restrict__ t2p) {
  int wid = threadIdx.x >> 6, lane = threadIdx.x & 63;
  int t = blockIdx.x * 4 + wid;
  double acc[NEXP];
#pragma unroll
  for (int e = 0; e < NEXP; ++e) acc[e] = 0.0;
  for (int d = lane; d < DD; d += 64) {
    double xv = x[(size_t)t * DD + d];
#pragma unroll
    for (int e = 0; e < NEXP; ++e) acc[e] += xv * u[e * DD + d];
  }
#pragma unroll
  for (int e = 0; e < NEXP; ++e)
    for (int m = 32; m; m >>= 1) acc[e] += __shfl_down(acc[e], m);
  float nv = (lane < 16) ? nu_part[t * 16 + lane] : 0.f;
  nv += __shfl_down(nv, 8); nv += __shfl_down(nv, 4);
  nv += __shfl_down(nv, 2); nv += __shfl_down(nv, 1);
  if (lane == 0) {
    double den = fmax(sqrt((double)nv), 1e-12) * (double)temp[0];
    double s[NEXP];
#pragma unroll
    for (int e = 0; e < NEXP; ++e) s[e] = acc[e] / den;
    int e1 = 0; double v1 = s[0];
    for (int e = 1; e < NEXP; ++e) if (s[e] > v1) { v1 = s[e]; e1 = e; }
    int e2 = -1; double v2 = -1e300;
    for (int e = 0; e < NEXP; ++e) if (e != e1 && s[e] > v2) { v2 = s[e]; e2 = e; }
    double z = exp(v2 - v1);
    double inv = 1.0 / (1.0 + z);
    t2e[t * 2] = e1; t2e[t * 2 + 1] = e2;
    t2p[t * 2] = (float)inv; t2p[t * 2 + 1] = (float)(z * inv);
  }
}

// meta: [0..7]=cnt [8..16]=padded offsets [17]=ntiles [18..25]=cursors [26..]=tile_expert
__global__ void k_count(const int* __restrict__ t2e, int* __restrict__ meta,
                        int* __restrict__ ptok, float* __restrict__ pp) {
  __shared__ int cnt[NEXP];
  int tid = threadIdx.x;
  for (int i = tid; i < PAIR_CAP; i += 256) { ptok[i] = 0; pp[i] = 0.f; }
  if (tid < NEXP) cnt[tid] = 0;
  __syncthreads();
  for (int i = tid; i < NTOK * 2; i += 256) atomicAdd(&cnt[t2e[i]], 1);
  __syncthreads();
  if (tid == 0) {
    int off = 0;
    for (int e = 0; e < NEXP; ++e) {
      meta[e] = cnt[e];
      meta[8 + e] = off;
      off += ((cnt[e] + EBM - 1) / EBM) * EBM;
    }
    meta[16] = off;
    meta[17] = off / EBM;
    for (int e = 0; e < NEXP; ++e) meta[18 + e] = 0;
    int ti = 0;
    for (int e = 0; e < NEXP; ++e) {
      int nt = (cnt[e] + EBM - 1) / EBM;
      for (int k = 0; k < nt; ++k) meta[26 + ti++] = e;
    }
  }
}

// parallel scatter (slot order arbitrary; output invariant: each pair -> one slot,
// out gets commutative atomic adds keyed by token)
__global__ void k_scatter(const int* __restrict__ t2e, const float* __restrict__ t2p,
                          int* __restrict__ meta, int* __restrict__ ptok,
                          float* __restrict__ pp) {
  int i = blockIdx.x * 256 + threadIdx.x;
  if (i >= NTOK * 2) return;
  int e = t2e[i];
  int slot = atomicAdd(&meta[18 + e], 1);
  int pos = meta[8 + e] + slot;
  ptok[pos] = i >> 1;
  pp[pos] = t2p[i];
}

// ---------------- unified GEMM: r13 best-measured core. 128x128, BK=32, 4 waves
// (2x2, each 64x64), dbuf LDS + tok_s/p_s (33792 B -> 4 blocks/CU),
// launch_bounds(256,4), global_load_lds(16), 2-barrier K-loop, conflict-free
// XOR f(m)=(m>>1)&3, 2-D XCD cache-block swizzle.
// K-chunking: kchunk elements per block (blockIdx.y = chunk index); K = row stride.
// EPI 0: proj -> per-row sum-of-squares into nu_part   (A=xbf, B=wpbf)
// EPI 1: gather-x @ W1t + b1, exact gelu -> h (bf16)   (A=xbf gathered, B=W1t[e])
// EPI 2: h @ W2t (+b2 on chunk 0), *p, atomicAdd out   (A=h,  B=W2t[e])
template <int EPI>
__launch_bounds__(256, 4)
__global__ void gemm_x(const ushort* __restrict__ Abase, const ushort* __restrict__ Bbase,
                       int K, int Brows, int kchunk,
                       const int* __restrict__ pair_tok, const float* __restrict__ pair_p,
                       const int* __restrict__ meta, const float* __restrict__ bias,
                       float* __restrict__ nu_part, ushort* __restrict__ hout,
                       float* __restrict__ outp, int g_tiles, int nby, int tile0) {
  __shared__ ushort As[2][EBM * EBK];   // 2 x 8KB
  __shared__ ushort Bs[2][EBN * EBK];   // 2 x 8KB
  __shared__ int tok_s[EBM];
  __shared__ float p_s[EBM];

  const int tid = threadIdx.x;          // 256
  const int lane = tid & 63;
  const int wid = tid >> 6;             // 4 waves
  const int k0 = blockIdx.y * kchunk;   // K-chunk base (elements)

  // ---- 2-D XCD cache-blocking swizzle (r=2 tile-halves x c=4 panel-quarters).
  int tile, nb;
  {
    int bid = blockIdx.x;
    if ((g_tiles & 1) == 0 && (nby & 3) == 0) {
      int x = bid & 7, b = bid >> 3;
      int i = x >> 2, j = x & 3;            // tile-half, panel-quarter
      int nt = g_tiles >> 1, np = nby >> 2;
      int t_loc = b / np, p_loc = b - t_loc * np;
      tile = i * nt + t_loc;
      nb = j * np + p_loc;
    } else {
      tile = bid % g_tiles;
      nb = bid / g_tiles;
    }
  }
  tile += tile0;

  int expert = 0;
  if constexpr (EPI != 0) {
    if (tile >= meta[17]) return;
    expert = meta[26 + tile];
    if (tid < EBM) {
      int pr = tile * EBM + tid;
      tok_s[tid] = pair_tok[pr];
      p_s[tid] = pair_p[pr];
    }
    __syncthreads();
  }

  const char* Ac = (const char*)Abase;
  const char* Bc = (const char*)(Bbase + (size_t)expert * Brows * K);

  // K-step tile = 512 chunks of 16B per operand; 2 groups of 256.
  // chunk c: m=c>>2, cc=c&3. Source pre-swizzled cc ^= (m>>1)&3 (conflict-free).
  const char* asrc[2];
  const char* bsrc[2];
#pragma unroll
  for (int i = 0; i < 2; ++i) {
    int c = i * 256 + tid;
    int m = c >> 2, cc = c & 3;
    int sw = (cc ^ ((m >> 1) & 3)) << 4;
    int arow;
    if constexpr (EPI == 1) arow = tok_s[m];
    else if constexpr (EPI == 2) arow = (tile - tile0) * EBM + m;
    else arow = tile * EBM + m;
    asrc[i] = Ac + ((size_t)arow * K + k0) * 2 + sw;
    bsrc[i] = Bc + ((size_t)(nb * EBN + m) * K + k0) * 2 + sw;
  }

  const int wr = wid >> 1, wc = wid & 1;     // 2x2 waves, each 64x64 of C
  const int l15 = lane & 15, lg = lane >> 4;
  const int fxor = (l15 >> 1) & 3;           // (r>>1)&3 for r = base16 + l15

  f32x4 acc[4][4];
#pragma unroll
  for (int a = 0; a < 4; ++a)
#pragma unroll
    for (int b = 0; b < 4; ++b) acc[a][b] = (f32x4){0.f, 0.f, 0.f, 0.f};

  const int nk = kchunk / EBK;

  // prologue stage -> buf 0   (dest = wave-uniform base; lanes append *16)
#pragma unroll
  for (int i = 0; i < 2; ++i) {
    async16(asrc[i], (char*)(&As[0][0]) + (i * 256 + wid * 64) * 16);
    async16(bsrc[i], (char*)(&Bs[0][0]) + (i * 256 + wid * 64) * 16);
  }

  for (int kt = 0; kt < nk; ++kt) {
    const int cur = kt & 1;
    __syncthreads();  // compiler drains vmcnt before barrier -> buf[cur] ready
    if (kt + 1 < nk) {
      const size_t ko = (size_t)(kt + 1) * EBK * 2;
#pragma unroll
      for (int i = 0; i < 2; ++i) {
        async16(asrc[i] + ko, (char*)(&As[cur ^ 1][0]) + (i * 256 + wid * 64) * 16);
        async16(bsrc[i] + ko, (char*)(&Bs[cur ^ 1][0]) + (i * 256 + wid * 64) * 16);
      }
    }
    const char* Ab = (const char*)(&As[cur][0]);
    const char* Bb = (const char*)(&Bs[cur][0]);
    bf16x8 af[4], bfr[4];
#pragma unroll
    for (int fi = 0; fi < 4; ++fi) {
      int r = wr * 64 + fi * 16 + l15;
      af[fi] = *(const bf16x8*)(Ab + r * 64 + (lg ^ fxor) * 16);
    }
#pragma unroll
    for (int fj = 0; fj < 4; ++fj) {
      int r = wc * 64 + fj * 16 + l15;
      bfr[fj] = *(const bf16x8*)(Bb + r * 64 + (lg ^ fxor) * 16);
    }
#pragma unroll
    for (int fi = 0; fi < 4; ++fi)
#pragma unroll
      for (int fj = 0; fj < 4; ++fj)
        acc[fi][fj] =
            __builtin_amdgcn_mfma_f32_16x16x32_bf16(af[fi], bfr[fj], acc[fi][fj], 0, 0, 0);
  }

  // ---------------- epilogue ----------------
  if constexpr (EPI == 0) {
    // per-row sum of squares over this block's 128 cols -> nu_part[row][nb*2+wc]
#pragma unroll
    for (int fi = 0; fi < 4; ++fi) {
#pragma unroll
      for (int j = 0; j < 4; ++j) {
        float s = 0.f;
#pragma unroll
        for (int fj = 0; fj < 4; ++fj) { float v = acc[fi][fj][j]; s += v * v; }
        s += __shfl_xor(s, 1); s += __shfl_xor(s, 2);
        s += __shfl_xor(s, 4); s += __shfl_xor(s, 8);
        if (l15 == 0) {
          int row = tile * EBM + wr * 64 + fi * 16 + lg * 4 + j;
          nu_part[row * 16 + nb * 2 + wc] = s;
        }
      }
    }
  } else if constexpr (EPI == 1) {
    float bv[4];
#pragma unroll
    for (int fj = 0; fj < 4; ++fj)
      bv[fj] = bias[expert * FF + nb * EBN + wc * 64 + fj * 16 + l15];
#pragma unroll
    for (int fi = 0; fi < 4; ++fi)
#pragma unroll
      for (int fj = 0; fj < 4; ++fj)
#pragma unroll
        for (int j = 0; j < 4; ++j) {
          float v = acc[fi][fj][j] + bv[fj];
          float g = 0.5f * v * (1.0f + erff(v * 0.70710678118654752f));  // exact gelu
          int rl = wr * 64 + fi * 16 + lg * 4 + j;
          size_t grow = (size_t)(tile - tile0) * EBM + rl;
          int col = nb * EBN + wc * 64 + fj * 16 + l15;
          hout[grow * FF + col] = f2bf(g);
        }
  } else {
    float bv[4];
    const float bgate = (k0 == 0) ? 1.f : 0.f;   // bias added by chunk 0 only
#pragma unroll
    for (int fj = 0; fj < 4; ++fj)
      bv[fj] = bgate * bias[expert * DD + nb * EBN + wc * 64 + fj * 16 + l15];
#pragma unroll
    for (int fi = 0; fi < 4; ++fi) {
      int rl = wr * 64 + fi * 16 + lg * 4;
#pragma unroll
      for (int j = 0; j < 4; ++j) {
        int tok = tok_s[rl + j];
        float p = p_s[rl + j];
#pragma unroll
        for (int fj = 0; fj < 4; ++fj) {
          float v = (acc[fi][fj][j] + bv[fj]) * p;
          int col = nb * EBN + wc * 64 + fj * 16 + l15;
          // 4 commutative f32 adds/elem (2 experts x 2 K-chunks); ULP-level
          // order jitter only, far below the 0.05 absmax threshold.
          atomicAdd(outp + (size_t)tok * DD + col, v);
        }
      }
    }
  }
}

// ---------------- host ----------------

extern "C" void kernel_launch(void* const* d_in, const int* in_sizes, int n_in,
                              void* d_out, int out_size, void* d_ws, size_t ws_size,
                              hipStream_t stream) {
  const float* x = (const float*)d_in[0];
  const float* wp = (const float*)d_in[1];
  const float* sim = (const float*)d_in[2];
  const float* temp = (const float*)d_in[3];
  const float* w1 = (const float*)d_in[4];
  const float* b1 = (const float*)d_in[5];
  const float* w2 = (const float*)d_in[6];
  const float* b2 = (const float*)d_in[7];
  float* out = (float*)d_out;

  char* w = (char*)d_ws;
  size_t off = 0;
  auto alloc = [&](size_t sz) {
    char* p = w + off;
    off = (off + sz + 255) & ~(size_t)255;
    return p;
  };
  double* u = (double*)alloc((size_t)NEXP * DD * 8);
  double* u_part = (double*)alloc((size_t)4 * NEXP * DD * 8);
  float* nu_part = (float*)alloc((size_t)NTOK * 16 * 4);
  int* t2e = (int*)alloc((size_t)NTOK * 2 * 4);
  float* t2p = (float*)alloc((size_t)NTOK * 2 * 4);
  int* meta = (int*)alloc(512);
  int* ptok = (int*)alloc((size_t)PAIR_CAP * 4);
  float* pp = (float*)alloc((size_t)PAIR_CAP * 4);
  ushort* xbf = (ushort*)alloc((size_t)NTOK * DD * 2);
  ushort* wpbf = (ushort*)alloc((size_t)DD * DD * 2);
  ushort* w1t = (ushort*)alloc((size_t)NEXP * DD * FF * 2);
  ushort* w2t = (ushort*)alloc((size_t)NEXP * DD * FF * 2);
  size_t havail = (ws_size > off) ? (ws_size - off) : 0;
  int G = (int)(havail / ((size_t)EBM * FF * 2));   // 1MB per tile of h
  if (G > TILES_MAX) G = TILES_MAX;
  if (G >= 8) G &= ~7;                              // multiple of 8 (even + full XCD rounds)
  if (G < 1) G = 1;
  ushort* h = (ushort*)(w + off);

  hipMemsetAsync(d_out, 0, (size_t)out_size * 4, stream);

  k_convert4<<<dim3(NTOK * DD / 4 / 256), 256, 0, stream>>>((const float4*)x, xbf, NTOK * DD / 4);
  k_convert4<<<dim3(DD * DD / 4 / 256), 256, 0, stream>>>((const float4*)wp, wpbf, DD * DD / 4);
  k_transpose<<<dim3(FF / 64, DD / 128, NEXP), 256, 0, stream>>>(w1, w1t, DD, FF);
  k_transpose<<<dim3(DD / 64, FF / 128, NEXP), 256, 0, stream>>>(w2, w2t, FF, DD);
  k_u<<<dim3(DD / 256, NEXP, 4), 256, 0, stream>>>(wp, sim, u_part);
  k_ured<<<dim3(NEXP * DD / 256), 256, 0, stream>>>(u_part, u);
  gemm_x<0><<<dim3((NTOK / EBM) * (DD / EBN)), 256, 0, stream>>>(
      xbf, wpbf, DD, DD, DD, nullptr, nullptr, nullptr, nullptr, nu_part, nullptr, nullptr,
      NTOK / EBM, DD / EBN, 0);
  k_gate<<<dim3(NTOK / 4), 256, 0, stream>>>(x, u, nu_part, temp, t2e, t2p);
  k_count<<<1, 256, 0, stream>>>(t2e, meta, ptok, pp);
  k_scatter<<<dim3(NTOK * 2 / 256), 256, 0, stream>>>(t2e, t2p, meta, ptok, pp);

  for (int t0 = 0; t0 < TILES_MAX; t0 += G) {
    int g = TILES_MAX - t0;
    if (g > G) g = G;
    gemm_x<1><<<dim3(g * (FF / EBN)), 256, 0, stream>>>(
        xbf, w1t, DD, FF, DD, ptok, pp, meta, b1, nullptr, h, nullptr, g, FF / EBN, t0);
    gemm_x<2><<<dim3(g * (DD / EBN), 2), 256, 0, stream>>>(
        h, w2t, FF, DD, FF / 2, ptok, pp, meta, b2, nullptr, nullptr, out, g, DD / EBN, t0);
  }
}

// Round 16
// 475.908 us; speedup vs baseline: 1.1414x; 1.1414x over previous
//
#include <hip/hip_runtime.h>
#include <hip/hip_bf16.h>
#include <math.h>

// MoE MLP, MI355X. B=2,S=2048 -> NTOK=4096 tokens, D=1024, F=4096, E=8, top2.
#define NTOK 4096
#define DD 1024
#define FF 4096
#define NEXP 8
#define EBM 128          // tile M
#define EBN 128          // tile N
#define EBK 32           // K-step -> 33.8KB LDS -> 4 blocks/CU (r10 measured optimum)
#define PAIR_CAP 9216    // 8192 pairs + 8*127 pad, rounded to 128
#define TILES_MAX 72     // PAIR_CAP / 128

typedef short bf16x8 __attribute__((ext_vector_type(8)));
typedef float f32x4 __attribute__((ext_vector_type(4)));
typedef unsigned short u16x8 __attribute__((ext_vector_type(8)));

__device__ __forceinline__ ushort f2bf(float x) {
  unsigned u = __float_as_uint(x);
  unsigned r = (u + 0x7FFFu + ((u >> 16) & 1u)) >> 16;
  return (ushort)r;
}

__device__ __forceinline__ void async16(const void* g, void* l) {
  __builtin_amdgcn_global_load_lds(
      (const __attribute__((address_space(1))) char*)g,
      (__attribute__((address_space(3))) char*)l, 16, 0, 0);
}

// ---------------- small kernels ----------------

// fused convert: x (NTOK*DD) then wp (DD*DD), f32 -> bf16, float4-vectorized
__global__ void k_convert2(const float4* __restrict__ x, ushort* __restrict__ xb,
                           const float4* __restrict__ wp, ushort* __restrict__ wb) {
  int i = blockIdx.x * 256 + threadIdx.x;
  const int n4x = NTOK * DD / 4;
  const float4* s;
  ushort* d;
  if (i < n4x) {
    s = x; d = xb;
  } else {
    i -= n4x;
    if (i >= DD * DD / 4) return;
    s = wp; d = wb;
  }
  float4 v = s[i];
  ushort4 o;
  o.x = f2bf(v.x); o.y = f2bf(v.y); o.z = f2bf(v.z); o.w = f2bf(v.w);
  *(ushort4*)(d + (size_t)i * 4) = o;
}

// fused transpose: [E][R][C] f32 -> [E][C][R] bf16 for W1 (R=DD,C=FF) and
// W2 (R=FF,C=DD). Flat grid: bid<4096 -> W1, else W2. 128r x 64c tiles.
__global__ void k_transpose2(const float* __restrict__ w1, const float* __restrict__ w2,
                             ushort* __restrict__ d1, ushort* __restrict__ d2) {
  __shared__ float tile[128][65];
  int bid = blockIdx.x;
  const float* s;
  ushort* d;
  int R, C, bx, by;
  if (bid < 4096) {              // W1: x=FF/64=64, y=DD/128=8, e=8
    int e = bid >> 9, rem = bid & 511;
    by = rem >> 6; bx = rem & 63;
    R = DD; C = FF;
    s = w1 + (size_t)e * R * C; d = d1 + (size_t)e * R * C;
  } else {                       // W2: x=DD/64=16, y=FF/128=32, e=8
    bid -= 4096;
    int e = bid >> 9, rem = bid & 511;
    by = rem >> 4; bx = rem & 15;
    R = FF; C = DD;
    s = w2 + (size_t)e * R * C; d = d2 + (size_t)e * R * C;
  }
  int c0 = bx * 64, r0 = by * 128;
  int tid = threadIdx.x;               // 256
  int rr0 = tid >> 4;                  // 0..15
  int cc4 = (tid & 15) * 4;            // 0..60
#pragma unroll
  for (int ps = 0; ps < 8; ++ps) {
    int r = ps * 16 + rr0;
    float4 v = *(const float4*)&s[(size_t)(r0 + r) * C + c0 + cc4];
    tile[r][cc4 + 0] = v.x; tile[r][cc4 + 1] = v.y;
    tile[r][cc4 + 2] = v.z; tile[r][cc4 + 3] = v.w;
  }
  __syncthreads();
  int cw = tid >> 4;                   // 0..15
  int rp = (tid & 15) * 8;             // 0..120
#pragma unroll
  for (int pass = 0; pass < 4; ++pass) {
    int c = pass * 16 + cw;
    u16x8 o;
#pragma unroll
    for (int k = 0; k < 8; ++k) o[k] = f2bf(tile[rp + k][c]);
    *(u16x8*)&d[(size_t)(c0 + c) * R + r0 + rp] = o;
  }
}

// u_part[kc][e][d] = (sum_{o in kc-chunk} Wp[o][d]*sim[e][o]) / max(||sim_e||,eps)
__global__ void k_u(const float* __restrict__ wp, const float* __restrict__ sim,
                    double* __restrict__ u_part) {
  __shared__ double sred[256];
  int tid = threadIdx.x;
  int dblk = blockIdx.x, e = blockIdx.y, kc = blockIdx.z;
  double s = 0.0;
#pragma unroll
  for (int j = 0; j < 4; ++j) {
    double v = sim[e * DD + j * 256 + tid];
    s += v * v;
  }
  sred[tid] = s;
  __syncthreads();
  for (int m = 128; m; m >>= 1) {
    if (tid < m) sred[tid] += sred[tid + m];
    __syncthreads();
  }
  double sn = fmax(sqrt(sred[0]), 1e-12);
  int d = dblk * 256 + tid;
  int o0 = kc * 256;
  double acc = 0.0;
#pragma unroll 8
  for (int o = o0; o < o0 + 256; ++o)
    acc += (double)wp[(size_t)o * DD + d] * (double)sim[e * DD + o];
  u_part[((size_t)kc * NEXP + e) * DD + d] = acc / sn;
}

// u = sum of 4 k-partials (deterministic)
__global__ void k_ured(const double* __restrict__ up, double* __restrict__ u) {
  int i = blockIdx.x * 256 + threadIdx.x;   // 8192
  u[i] = (up[i] + up[8192 + i]) + (up[16384 + i] + up[24576 + i]);
}

// per-token: n_e = x . u_e (f64); nu from nu_part (32 columns) inline; top2 + softmax
__global__ void k_gate(const float* __restrict__ x, const double* __restrict__ u,
                       const float* __restrict__ nu_part, const float* __restrict__ temp,
                       int* __restrict__ t2e, float* __restrict__ t2p) {
  int wid = threadIdx.x >> 6, lane = threadIdx.x & 63;
  int t = blockIdx.x * 4 + wid;
  double acc[NEXP];
#pragma unroll
  for (int e = 0; e < NEXP; ++e) acc[e] = 0.0;
  for (int d = lane; d < DD; d += 64) {
    double xv = x[(size_t)t * DD + d];
#pragma unroll
    for (int e = 0; e < NEXP; ++e) acc[e] += xv * u[e * DD + d];
  }
#pragma unroll
  for (int e = 0; e < NEXP; ++e)
    for (int m = 32; m; m >>= 1) acc[e] += __shfl_down(acc[e], m);
  float nv = (lane < 32) ? nu_part[t * 32 + lane] : 0.f;
  nv += __shfl_down(nv, 16); nv += __shfl_down(nv, 8); nv += __shfl_down(nv, 4);
  nv += __shfl_down(nv, 2); nv += __shfl_down(nv, 1);
  if (lane == 0) {
    double den = fmax(sqrt((double)nv), 1e-12) * (double)temp[0];
    double s[NEXP];
#pragma unroll
    for (int e = 0; e < NEXP; ++e) s[e] = acc[e] / den;
    int e1 = 0; double v1 = s[0];
    for (int e = 1; e < NEXP; ++e) if (s[e] > v1) { v1 = s[e]; e1 = e; }
    int e2 = -1; double v2 = -1e300;
    for (int e = 0; e < NEXP; ++e) if (e != e1 && s[e] > v2) { v2 = s[e]; e2 = e; }
    double z = exp(v2 - v1);
    double inv = 1.0 / (1.0 + z);
    t2e[t * 2] = e1; t2e[t * 2 + 1] = e2;
    t2p[t * 2] = (float)inv; t2p[t * 2 + 1] = (float)(z * inv);
  }
}

// meta: [0..7]=cnt [8..16]=padded offsets [17]=ntiles [18..25]=cursors [26..]=tile_expert
__global__ void k_count(const int* __restrict__ t2e, int* __restrict__ meta,
                        int* __restrict__ ptok, float* __restrict__ pp) {
  __shared__ int cnt[NEXP];
  int tid = threadIdx.x;
  for (int i = tid; i < PAIR_CAP; i += 256) { ptok[i] = 0; pp[i] = 0.f; }
  if (tid < NEXP) cnt[tid] = 0;
  __syncthreads();
  for (int i = tid; i < NTOK * 2; i += 256) atomicAdd(&cnt[t2e[i]], 1);
  __syncthreads();
  if (tid == 0) {
    int off = 0;
    for (int e = 0; e < NEXP; ++e) {
      meta[e] = cnt[e];
      meta[8 + e] = off;
      off += ((cnt[e] + EBM - 1) / EBM) * EBM;
    }
    meta[16] = off;
    meta[17] = off / EBM;
    for (int e = 0; e < NEXP; ++e) meta[18 + e] = 0;
    int ti = 0;
    for (int e = 0; e < NEXP; ++e) {
      int nt = (cnt[e] + EBM - 1) / EBM;
      for (int k = 0; k < nt; ++k) meta[26 + ti++] = e;
    }
  }
}

// parallel scatter (slot order arbitrary; output invariant: each pair -> one slot,
// out gets commutative atomic adds keyed by token)
__global__ void k_scatter(const int* __restrict__ t2e, const float* __restrict__ t2p,
                          int* __restrict__ meta, int* __restrict__ ptok,
                          float* __restrict__ pp) {
  int i = blockIdx.x * 256 + threadIdx.x;
  if (i >= NTOK * 2) return;
  int e = t2e[i];
  int slot = atomicAdd(&meta[18 + e], 1);
  int pos = meta[8 + e] + slot;
  ptok[pos] = i >> 1;
  pp[pos] = t2p[i];
}

// ---------------- unified GEMM: r13 best-measured core. 128x128, BK=32, 4 waves
// (2x2, each 64x64), dbuf LDS + tok_s/p_s (33792 B -> 4 blocks/CU),
// launch_bounds(256,4), global_load_lds(16), 2-barrier K-loop, conflict-free
// XOR f(m)=(m>>1)&3, 2-D XCD cache-block swizzle.
// K-chunking (proj only): kchunk elems/block, blockIdx.y = chunk; K = row stride.
// EPI 0: proj -> per-row sum-of-squares into nu_part[row][32] (chunk-split cols)
// EPI 1: gather-x @ W1t + b1, exact gelu -> h (bf16)   (A=xbf gathered, B=W1t[e])
// EPI 2: h @ W2t + b2, *p, atomicAdd into out          (A=h,  B=W2t[e])
template <int EPI>
__launch_bounds__(256, 4)
__global__ void gemm_x(const ushort* __restrict__ Abase, const ushort* __restrict__ Bbase,
                       int K, int Brows, int kchunk,
                       const int* __restrict__ pair_tok, const float* __restrict__ pair_p,
                       const int* __restrict__ meta, const float* __restrict__ bias,
                       float* __restrict__ nu_part, ushort* __restrict__ hout,
                       float* __restrict__ outp, int g_tiles, int nby, int tile0) {
  __shared__ ushort As[2][EBM * EBK];   // 2 x 8KB
  __shared__ ushort Bs[2][EBN * EBK];   // 2 x 8KB
  __shared__ int tok_s[EBM];
  __shared__ float p_s[EBM];

  const int tid = threadIdx.x;          // 256
  const int lane = tid & 63;
  const int wid = tid >> 6;             // 4 waves
  const int k0 = blockIdx.y * kchunk;   // K-chunk base (elements)

  // ---- 2-D XCD cache-blocking swizzle (r=2 tile-halves x c=4 panel-quarters).
  int tile, nb;
  {
    int bid = blockIdx.x;
    if ((g_tiles & 1) == 0 && (nby & 3) == 0) {
      int x = bid & 7, b = bid >> 3;
      int i = x >> 2, j = x & 3;            // tile-half, panel-quarter
      int nt = g_tiles >> 1, np = nby >> 2;
      int t_loc = b / np, p_loc = b - t_loc * np;
      tile = i * nt + t_loc;
      nb = j * np + p_loc;
    } else {
      tile = bid % g_tiles;
      nb = bid / g_tiles;
    }
  }
  tile += tile0;

  int expert = 0;
  if constexpr (EPI != 0) {
    if (tile >= meta[17]) return;
    expert = meta[26 + tile];
    if (tid < EBM) {
      int pr = tile * EBM + tid;
      tok_s[tid] = pair_tok[pr];
      p_s[tid] = pair_p[pr];
    }
    __syncthreads();
  }

  const char* Ac = (const char*)Abase;
  const char* Bc = (const char*)(Bbase + (size_t)expert * Brows * K);

  // K-step tile = 512 chunks of 16B per operand; 2 groups of 256.
  // chunk c: m=c>>2, cc=c&3. Source pre-swizzled cc ^= (m>>1)&3 (conflict-free).
  const char* asrc[2];
  const char* bsrc[2];
#pragma unroll
  for (int i = 0; i < 2; ++i) {
    int c = i * 256 + tid;
    int m = c >> 2, cc = c & 3;
    int sw = (cc ^ ((m >> 1) & 3)) << 4;
    int arow;
    if constexpr (EPI == 1) arow = tok_s[m];
    else if constexpr (EPI == 2) arow = (tile - tile0) * EBM + m;
    else arow = tile * EBM + m;
    asrc[i] = Ac + ((size_t)arow * K + k0) * 2 + sw;
    bsrc[i] = Bc + ((size_t)(nb * EBN + m) * K + k0) * 2 + sw;
  }

  const int wr = wid >> 1, wc = wid & 1;     // 2x2 waves, each 64x64 of C
  const int l15 = lane & 15, lg = lane >> 4;
  const int fxor = (l15 >> 1) & 3;           // (r>>1)&3 for r = base16 + l15

  f32x4 acc[4][4];
#pragma unroll
  for (int a = 0; a < 4; ++a)
#pragma unroll
    for (int b = 0; b < 4; ++b) acc[a][b] = (f32x4){0.f, 0.f, 0.f, 0.f};

  const int nk = kchunk / EBK;

  // prologue stage -> buf 0   (dest = wave-uniform base; lanes append *16)
#pragma unroll
  for (int i = 0; i < 2; ++i) {
    async16(asrc[i], (char*)(&As[0][0]) + (i * 256 + wid * 64) * 16);
    async16(bsrc[i], (char*)(&Bs[0][0]) + (i * 256 + wid * 64) * 16);
  }

  for (int kt = 0; kt < nk; ++kt) {
    const int cur = kt & 1;
    __syncthreads();  // compiler drains vmcnt before barrier -> buf[cur] ready
    if (kt + 1 < nk) {
      const size_t ko = (size_t)(kt + 1) * EBK * 2;
#pragma unroll
      for (int i = 0; i < 2; ++i) {
        async16(asrc[i] + ko, (char*)(&As[cur ^ 1][0]) + (i * 256 + wid * 64) * 16);
        async16(bsrc[i] + ko, (char*)(&Bs[cur ^ 1][0]) + (i * 256 + wid * 64) * 16);
      }
    }
    const char* Ab = (const char*)(&As[cur][0]);
    const char* Bb = (const char*)(&Bs[cur][0]);
    bf16x8 af[4], bfr[4];
#pragma unroll
    for (int fi = 0; fi < 4; ++fi) {
      int r = wr * 64 + fi * 16 + l15;
      af[fi] = *(const bf16x8*)(Ab + r * 64 + (lg ^ fxor) * 16);
    }
#pragma unroll
    for (int fj = 0; fj < 4; ++fj) {
      int r = wc * 64 + fj * 16 + l15;
      bfr[fj] = *(const bf16x8*)(Bb + r * 64 + (lg ^ fxor) * 16);
    }
#pragma unroll
    for (int fi = 0; fi < 4; ++fi)
#pragma unroll
      for (int fj = 0; fj < 4; ++fj)
        acc[fi][fj] =
            __builtin_amdgcn_mfma_f32_16x16x32_bf16(af[fi], bfr[fj], acc[fi][fj], 0, 0, 0);
  }

  // ---------------- epilogue ----------------
  if constexpr (EPI == 0) {
    // per-row sum of squares over this block's 128 cols & K-chunk
    // -> nu_part[row][blockIdx.y*16 + nb*2 + wc]
#pragma unroll
    for (int fi = 0; fi < 4; ++fi) {
#pragma unroll
      for (int j = 0; j < 4; ++j) {
        float s = 0.f;
#pragma unroll
        for (int fj = 0; fj < 4; ++fj) { float v = acc[fi][fj][j]; s += v * v; }
        s += __shfl_xor(s, 1); s += __shfl_xor(s, 2);
        s += __shfl_xor(s, 4); s += __shfl_xor(s, 8);
        if (l15 == 0) {
          int row = tile * EBM + wr * 64 + fi * 16 + lg * 4 + j;
          nu_part[row * 32 + blockIdx.y * 16 + nb * 2 + wc] = s;
        }
      }
    }
  } else if constexpr (EPI == 1) {
    float bv[4];
#pragma unroll
    for (int fj = 0; fj < 4; ++fj)
      bv[fj] = bias[expert * FF + nb * EBN + wc * 64 + fj * 16 + l15];
#pragma unroll
    for (int fi = 0; fi < 4; ++fi)
#pragma unroll
      for (int fj = 0; fj < 4; ++fj)
#pragma unroll
        for (int j = 0; j < 4; ++j) {
          float v = acc[fi][fj][j] + bv[fj];
          float g = 0.5f * v * (1.0f + erff(v * 0.70710678118654752f));  // exact gelu
          int rl = wr * 64 + fi * 16 + lg * 4 + j;
          size_t grow = (size_t)(tile - tile0) * EBM + rl;
          int col = nb * EBN + wc * 64 + fj * 16 + l15;
          hout[grow * FF + col] = f2bf(g);
        }
  } else {
    float bv[4];
#pragma unroll
    for (int fj = 0; fj < 4; ++fj)
      bv[fj] = bias[expert * DD + nb * EBN + wc * 64 + fj * 16 + l15];
#pragma unroll
    for (int fi = 0; fi < 4; ++fi) {
      int rl = wr * 64 + fi * 16 + lg * 4;
#pragma unroll
      for (int j = 0; j < 4; ++j) {
        int tok = tok_s[rl + j];
        float p = p_s[rl + j];
#pragma unroll
        for (int fj = 0; fj < 4; ++fj) {
          float v = (acc[fi][fj][j] + bv[fj]) * p;
          int col = nb * EBN + wc * 64 + fj * 16 + l15;
          atomicAdd(outp + (size_t)tok * DD + col, v);  // exactly 2 adds/elem, commutative -> deterministic
        }
      }
    }
  }
}

// ---------------- host ----------------

extern "C" void kernel_launch(void* const* d_in, const int* in_sizes, int n_in,
                              void* d_out, int out_size, void* d_ws, size_t ws_size,
                              hipStream_t stream) {
  const float* x = (const float*)d_in[0];
  const float* wp = (const float*)d_in[1];
  const float* sim = (const float*)d_in[2];
  const float* temp = (const float*)d_in[3];
  const float* w1 = (const float*)d_in[4];
  const float* b1 = (const float*)d_in[5];
  const float* w2 = (const float*)d_in[6];
  const float* b2 = (const float*)d_in[7];
  float* out = (float*)d_out;

  char* w = (char*)d_ws;
  size_t off = 0;
  auto alloc = [&](size_t sz) {
    char* p = w + off;
    off = (off + sz + 255) & ~(size_t)255;
    return p;
  };
  double* u = (double*)alloc((size_t)NEXP * DD * 8);
  double* u_part = (double*)alloc((size_t)4 * NEXP * DD * 8);
  float* nu_part = (float*)alloc((size_t)NTOK * 32 * 4);
  int* t2e = (int*)alloc((size_t)NTOK * 2 * 4);
  float* t2p = (float*)alloc((size_t)NTOK * 2 * 4);
  int* meta = (int*)alloc(512);
  int* ptok = (int*)alloc((size_t)PAIR_CAP * 4);
  float* pp = (float*)alloc((size_t)PAIR_CAP * 4);
  ushort* xbf = (ushort*)alloc((size_t)NTOK * DD * 2);
  ushort* wpbf = (ushort*)alloc((size_t)DD * DD * 2);
  ushort* w1t = (ushort*)alloc((size_t)NEXP * DD * FF * 2);
  ushort* w2t = (ushort*)alloc((size_t)NEXP * DD * FF * 2);
  size_t havail = (ws_size > off) ? (ws_size - off) : 0;
  int G = (int)(havail / ((size_t)EBM * FF * 2));   // 1MB per tile of h
  if (G > TILES_MAX) G = TILES_MAX;
  if (G >= 8) G &= ~7;                              // multiple of 8 (even + full XCD rounds)
  if (G < 1) G = 1;
  ushort* h = (ushort*)(w + off);

  hipMemsetAsync(d_out, 0, (size_t)out_size * 4, stream);

  k_convert2<<<dim3((NTOK * DD + DD * DD) / 4 / 256), 256, 0, stream>>>(
      (const float4*)x, xbf, (const float4*)wp, wpbf);
  k_transpose2<<<dim3(8192), 256, 0, stream>>>(w1, w2, w1t, w2t);
  k_u<<<dim3(DD / 256, NEXP, 4), 256, 0, stream>>>(wp, sim, u_part);
  k_ured<<<dim3(NEXP * DD / 256), 256, 0, stream>>>(u_part, u);
  gemm_x<0><<<dim3((NTOK / EBM) * (DD / EBN), 2), 256, 0, stream>>>(
      xbf, wpbf, DD, DD, DD / 2, nullptr, nullptr, nullptr, nullptr, nu_part, nullptr,
      nullptr, NTOK / EBM, DD / EBN, 0);
  k_gate<<<dim3(NTOK / 4), 256, 0, stream>>>(x, u, nu_part, temp, t2e, t2p);
  k_count<<<1, 256, 0, stream>>>(t2e, meta, ptok, pp);
  k_scatter<<<dim3(NTOK * 2 / 256), 256, 0, stream>>>(t2e, t2p, meta, ptok, pp);

  for (int t0 = 0; t0 < TILES_MAX; t0 += G) {
    int g = TILES_MAX - t0;
    if (g > G) g = G;
    gemm_x<1><<<dim3(g * (FF / EBN)), 256, 0, stream>>>(
        xbf, w1t, DD, FF, DD, ptok, pp, meta, b1, nullptr, h, nullptr, g, FF / EBN, t0);
    gemm_x<2><<<dim3(g * (DD / EBN)), 256, 0, stream>>>(
        h, w2t, FF, DD, FF, ptok, pp, meta, b2, nullptr, nullptr, out, g, DD / EBN, t0);
  }
}

// Round 17
// 472.306 us; speedup vs baseline: 1.1501x; 1.0076x over previous
//
#include <hip/hip_runtime.h>
#include <hip/hip_bf16.h>
#include <math.h>

// MoE MLP, MI355X. B=2,S=2048 -> NTOK=4096 tokens, D=1024, F=4096, E=8, top2.
#define NTOK 4096
#define DD 1024
#define FF 4096
#define NEXP 8
#define EBM 128          // tile M
#define EBN 128          // tile N
#define EBK 32           // K-step -> 33.8KB LDS -> 4 blocks/CU (r10 measured optimum)
#define PAIR_CAP 9216    // 8192 pairs + 8*127 pad, rounded to 128
#define TILES_MAX 72     // PAIR_CAP / 128
#define CONV_BLKS 5120   // (NTOK*DD + DD*DD)/4/256 exactly
#define TR_BLKS 8192     // 4096 (W1) + 4096 (W2)
#define KU_BLKS 128      // 4 dblk x 8 e x 4 kc

typedef short bf16x8 __attribute__((ext_vector_type(8)));
typedef float f32x4 __attribute__((ext_vector_type(4)));
typedef unsigned short u16x8 __attribute__((ext_vector_type(8)));

__device__ __forceinline__ ushort f2bf(float x) {
  unsigned u = __float_as_uint(x);
  unsigned r = (u + 0x7FFFu + ((u >> 16) & 1u)) >> 16;
  return (ushort)r;
}

__device__ __forceinline__ void async16(const void* g, void* l) {
  __builtin_amdgcn_global_load_lds(
      (const __attribute__((address_space(1))) char*)g,
      (__attribute__((address_space(3))) char*)l, 16, 0, 0);
}

// ---------------- fused preamble: converts + transposes + k_u (independent work,
// one flat grid -> co-scheduled, 2 fewer dispatch boundaries) ----------------
__global__ void k_pre(const float4* __restrict__ x4, ushort* __restrict__ xb,
                      const float4* __restrict__ wp4, ushort* __restrict__ wb,
                      const float* __restrict__ w1, const float* __restrict__ w2,
                      ushort* __restrict__ d1, ushort* __restrict__ d2,
                      const float* __restrict__ wp, const float* __restrict__ sim,
                      double* __restrict__ u_part) {
  __shared__ char smem[128 * 65 * 4];
  int bid = blockIdx.x;
  int tid = threadIdx.x;

  if (bid < CONV_BLKS) {
    // ---- segment A: f32 -> bf16 converts (x then Wp), float4-vectorized ----
    int i = bid * 256 + tid;
    const int n4x = NTOK * DD / 4;
    const float4* s;
    ushort* d;
    if (i < n4x) { s = x4; d = xb; }
    else { i -= n4x; s = wp4; d = wb; }   // grid sized exactly: i < DD*DD/4
    float4 v = s[i];
    ushort4 o;
    o.x = f2bf(v.x); o.y = f2bf(v.y); o.z = f2bf(v.z); o.w = f2bf(v.w);
    *(ushort4*)(d + (size_t)i * 4) = o;
    return;
  }
  bid -= CONV_BLKS;

  if (bid < TR_BLKS) {
    // ---- segment B: [E][R][C] f32 -> [E][C][R] bf16, 128r x 64c tiles ----
    float (*tile)[65] = (float(*)[65])smem;
    const float* s;
    ushort* d;
    int R, C, bx, by;
    if (bid < 4096) {              // W1: R=DD, C=FF; x=64, y=8, e=8
      int e = bid >> 9, rem = bid & 511;
      by = rem >> 6; bx = rem & 63;
      R = DD; C = FF;
      s = w1 + (size_t)e * R * C; d = d1 + (size_t)e * R * C;
    } else {                       // W2: R=FF, C=DD; x=16, y=32, e=8
      bid -= 4096;
      int e = bid >> 9, rem = bid & 511;
      by = rem >> 4; bx = rem & 15;
      R = FF; C = DD;
      s = w2 + (size_t)e * R * C; d = d2 + (size_t)e * R * C;
    }
    int c0 = bx * 64, r0 = by * 128;
    int rr0 = tid >> 4;
    int cc4 = (tid & 15) * 4;
#pragma unroll
    for (int ps = 0; ps < 8; ++ps) {
      int r = ps * 16 + rr0;
      float4 v = *(const float4*)&s[(size_t)(r0 + r) * C + c0 + cc4];
      tile[r][cc4 + 0] = v.x; tile[r][cc4 + 1] = v.y;
      tile[r][cc4 + 2] = v.z; tile[r][cc4 + 3] = v.w;
    }
    __syncthreads();
    int cw = tid >> 4;
    int rp = (tid & 15) * 8;
#pragma unroll
    for (int pass = 0; pass < 4; ++pass) {
      int c = pass * 16 + cw;
      u16x8 o;
#pragma unroll
      for (int k = 0; k < 8; ++k) o[k] = f2bf(tile[rp + k][c]);
      *(u16x8*)&d[(size_t)(c0 + c) * R + r0 + rp] = o;
    }
    return;
  }
  bid -= TR_BLKS;

  // ---- segment C: u_part[kc][e][d] (f64, simnorm folded in) ----
  {
    double* sred = (double*)smem;
    int dblk = bid & 3, e = (bid >> 2) & 7, kc = bid >> 5;
    double s = 0.0;
#pragma unroll
    for (int j = 0; j < 4; ++j) {
      double v = sim[e * DD + j * 256 + tid];
      s += v * v;
    }
    sred[tid] = s;
    __syncthreads();
    for (int m = 128; m; m >>= 1) {
      if (tid < m) sred[tid] += sred[tid + m];
      __syncthreads();
    }
    double sn = fmax(sqrt(sred[0]), 1e-12);
    int d = dblk * 256 + tid;
    int o0 = kc * 256;
    double acc = 0.0;
#pragma unroll 8
    for (int o = o0; o < o0 + 256; ++o)
      acc += (double)wp[(size_t)o * DD + d] * (double)sim[e * DD + o];
    u_part[((size_t)kc * NEXP + e) * DD + d] = acc / sn;
  }
}

// u = sum of 4 k-partials (deterministic)
__global__ void k_ured(const double* __restrict__ up, double* __restrict__ u) {
  int i = blockIdx.x * 256 + threadIdx.x;   // 8192
  u[i] = (up[i] + up[8192 + i]) + (up[16384 + i] + up[24576 + i]);
}

// per-token: n_e = x . u_e (f64); nu from nu_part (32 columns) inline; top2 + softmax
__global__ void k_gate(const float* __restrict__ x, const double* __restrict__ u,
                       const float* __restrict__ nu_part, const float* __restrict__ temp,
                       int* __restrict__ t2e, float* __restrict__ t2p) {
  int wid = threadIdx.x >> 6, lane = threadIdx.x & 63;
  int t = blockIdx.x * 4 + wid;
  double acc[NEXP];
#pragma unroll
  for (int e = 0; e < NEXP; ++e) acc[e] = 0.0;
  for (int d = lane; d < DD; d += 64) {
    double xv = x[(size_t)t * DD + d];
#pragma unroll
    for (int e = 0; e < NEXP; ++e) acc[e] += xv * u[e * DD + d];
  }
#pragma unroll
  for (int e = 0; e < NEXP; ++e)
    for (int m = 32; m; m >>= 1) acc[e] += __shfl_down(acc[e], m);
  float nv = (lane < 32) ? nu_part[t * 32 + lane] : 0.f;
  nv += __shfl_down(nv, 16); nv += __shfl_down(nv, 8); nv += __shfl_down(nv, 4);
  nv += __shfl_down(nv, 2); nv += __shfl_down(nv, 1);
  if (lane == 0) {
    double den = fmax(sqrt((double)nv), 1e-12) * (double)temp[0];
    double s[NEXP];
#pragma unroll
    for (int e = 0; e < NEXP; ++e) s[e] = acc[e] / den;
    int e1 = 0; double v1 = s[0];
    for (int e = 1; e < NEXP; ++e) if (s[e] > v1) { v1 = s[e]; e1 = e; }
    int e2 = -1; double v2 = -1e300;
    for (int e = 0; e < NEXP; ++e) if (e != e1 && s[e] > v2) { v2 = s[e]; e2 = e; }
    double z = exp(v2 - v1);
    double inv = 1.0 / (1.0 + z);
    t2e[t * 2] = e1; t2e[t * 2 + 1] = e2;
    t2p[t * 2] = (float)inv; t2p[t * 2 + 1] = (float)(z * inv);
  }
}

// meta: [0..7]=cnt [8..16]=padded offsets [17]=ntiles [18..25]=cursors [26..]=tile_expert
__global__ void k_count(const int* __restrict__ t2e, int* __restrict__ meta,
                        int* __restrict__ ptok, float* __restrict__ pp) {
  __shared__ int cnt[NEXP];
  int tid = threadIdx.x;
  for (int i = tid; i < PAIR_CAP; i += 256) { ptok[i] = 0; pp[i] = 0.f; }
  if (tid < NEXP) cnt[tid] = 0;
  __syncthreads();
  for (int i = tid; i < NTOK * 2; i += 256) atomicAdd(&cnt[t2e[i]], 1);
  __syncthreads();
  if (tid == 0) {
    int off = 0;
    for (int e = 0; e < NEXP; ++e) {
      meta[e] = cnt[e];
      meta[8 + e] = off;
      off += ((cnt[e] + EBM - 1) / EBM) * EBM;
    }
    meta[16] = off;
    meta[17] = off / EBM;
    for (int e = 0; e < NEXP; ++e) meta[18 + e] = 0;
    int ti = 0;
    for (int e = 0; e < NEXP; ++e) {
      int nt = (cnt[e] + EBM - 1) / EBM;
      for (int k = 0; k < nt; ++k) meta[26 + ti++] = e;
    }
  }
}

// parallel scatter (slot order arbitrary; output invariant: each pair -> one slot,
// out gets commutative atomic adds keyed by token)
__global__ void k_scatter(const int* __restrict__ t2e, const float* __restrict__ t2p,
                          int* __restrict__ meta, int* __restrict__ ptok,
                          float* __restrict__ pp) {
  int i = blockIdx.x * 256 + threadIdx.x;
  if (i >= NTOK * 2) return;
  int e = t2e[i];
  int slot = atomicAdd(&meta[18 + e], 1);
  int pos = meta[8 + e] + slot;
  ptok[pos] = i >> 1;
  pp[pos] = t2p[i];
}

// ---------------- unified GEMM: r13 best-measured core. 128x128, BK=32, 4 waves
// (2x2, each 64x64), dbuf LDS + tok_s/p_s (33792 B -> 4 blocks/CU),
// launch_bounds(256,4), global_load_lds(16), 2-barrier K-loop, conflict-free
// XOR f(m)=(m>>1)&3, 2-D XCD cache-block swizzle.
// K-chunking (proj only): kchunk elems/block, blockIdx.y = chunk; K = row stride.
// EPI 0: proj -> per-row sum-of-squares into nu_part[row][32] (chunk-split cols)
// EPI 1: gather-x @ W1t + b1, exact gelu -> h (bf16)   (A=xbf gathered, B=W1t[e])
// EPI 2: h @ W2t + b2, *p, atomicAdd into out          (A=h,  B=W2t[e])
template <int EPI>
__launch_bounds__(256, 4)
__global__ void gemm_x(const ushort* __restrict__ Abase, const ushort* __restrict__ Bbase,
                       int K, int Brows, int kchunk,
                       const int* __restrict__ pair_tok, const float* __restrict__ pair_p,
                       const int* __restrict__ meta, const float* __restrict__ bias,
                       float* __restrict__ nu_part, ushort* __restrict__ hout,
                       float* __restrict__ outp, int g_tiles, int nby, int tile0) {
  __shared__ ushort As[2][EBM * EBK];   // 2 x 8KB
  __shared__ ushort Bs[2][EBN * EBK];   // 2 x 8KB
  __shared__ int tok_s[EBM];
  __shared__ float p_s[EBM];

  const int tid = threadIdx.x;          // 256
  const int lane = tid & 63;
  const int wid = tid >> 6;             // 4 waves
  const int k0 = blockIdx.y * kchunk;   // K-chunk base (elements)

  // ---- 2-D XCD cache-blocking swizzle (r=2 tile-halves x c=4 panel-quarters).
  int tile, nb;
  {
    int bid = blockIdx.x;
    if ((g_tiles & 1) == 0 && (nby & 3) == 0) {
      int x = bid & 7, b = bid >> 3;
      int i = x >> 2, j = x & 3;            // tile-half, panel-quarter
      int nt = g_tiles >> 1, np = nby >> 2;
      int t_loc = b / np, p_loc = b - t_loc * np;
      tile = i * nt + t_loc;
      nb = j * np + p_loc;
    } else {
      tile = bid % g_tiles;
      nb = bid / g_tiles;
    }
  }
  tile += tile0;

  int expert = 0;
  if constexpr (EPI != 0) {
    if (tile >= meta[17]) return;
    expert = meta[26 + tile];
    if (tid < EBM) {
      int pr = tile * EBM + tid;
      tok_s[tid] = pair_tok[pr];
      p_s[tid] = pair_p[pr];
    }
    __syncthreads();
  }

  const char* Ac = (const char*)Abase;
  const char* Bc = (const char*)(Bbase + (size_t)expert * Brows * K);

  // K-step tile = 512 chunks of 16B per operand; 2 groups of 256.
  // chunk c: m=c>>2, cc=c&3. Source pre-swizzled cc ^= (m>>1)&3 (conflict-free).
  const char* asrc[2];
  const char* bsrc[2];
#pragma unroll
  for (int i = 0; i < 2; ++i) {
    int c = i * 256 + tid;
    int m = c >> 2, cc = c & 3;
    int sw = (cc ^ ((m >> 1) & 3)) << 4;
    int arow;
    if constexpr (EPI == 1) arow = tok_s[m];
    else if constexpr (EPI == 2) arow = (tile - tile0) * EBM + m;
    else arow = tile * EBM + m;
    asrc[i] = Ac + ((size_t)arow * K + k0) * 2 + sw;
    bsrc[i] = Bc + ((size_t)(nb * EBN + m) * K + k0) * 2 + sw;
  }

  const int wr = wid >> 1, wc = wid & 1;     // 2x2 waves, each 64x64 of C
  const int l15 = lane & 15, lg = lane >> 4;
  const int fxor = (l15 >> 1) & 3;           // (r>>1)&3 for r = base16 + l15

  f32x4 acc[4][4];
#pragma unroll
  for (int a = 0; a < 4; ++a)
#pragma unroll
    for (int b = 0; b < 4; ++b) acc[a][b] = (f32x4){0.f, 0.f, 0.f, 0.f};

  const int nk = kchunk / EBK;

  // prologue stage -> buf 0   (dest = wave-uniform base; lanes append *16)
#pragma unroll
  for (int i = 0; i < 2; ++i) {
    async16(asrc[i], (char*)(&As[0][0]) + (i * 256 + wid * 64) * 16);
    async16(bsrc[i], (char*)(&Bs[0][0]) + (i * 256 + wid * 64) * 16);
  }

  for (int kt = 0; kt < nk; ++kt) {
    const int cur = kt & 1;
    __syncthreads();  // compiler drains vmcnt before barrier -> buf[cur] ready
    if (kt + 1 < nk) {
      const size_t ko = (size_t)(kt + 1) * EBK * 2;
#pragma unroll
      for (int i = 0; i < 2; ++i) {
        async16(asrc[i] + ko, (char*)(&As[cur ^ 1][0]) + (i * 256 + wid * 64) * 16);
        async16(bsrc[i] + ko, (char*)(&Bs[cur ^ 1][0]) + (i * 256 + wid * 64) * 16);
      }
    }
    const char* Ab = (const char*)(&As[cur][0]);
    const char* Bb = (const char*)(&Bs[cur][0]);
    bf16x8 af[4], bfr[4];
#pragma unroll
    for (int fi = 0; fi < 4; ++fi) {
      int r = wr * 64 + fi * 16 + l15;
      af[fi] = *(const bf16x8*)(Ab + r * 64 + (lg ^ fxor) * 16);
    }
#pragma unroll
    for (int fj = 0; fj < 4; ++fj) {
      int r = wc * 64 + fj * 16 + l15;
      bfr[fj] = *(const bf16x8*)(Bb + r * 64 + (lg ^ fxor) * 16);
    }
#pragma unroll
    for (int fi = 0; fi < 4; ++fi)
#pragma unroll
      for (int fj = 0; fj < 4; ++fj)
        acc[fi][fj] =
            __builtin_amdgcn_mfma_f32_16x16x32_bf16(af[fi], bfr[fj], acc[fi][fj], 0, 0, 0);
  }

  // ---------------- epilogue ----------------
  if constexpr (EPI == 0) {
    // per-row sum of squares over this block's 128 cols & K-chunk
    // -> nu_part[row][blockIdx.y*16 + nb*2 + wc]
#pragma unroll
    for (int fi = 0; fi < 4; ++fi) {
#pragma unroll
      for (int j = 0; j < 4; ++j) {
        float s = 0.f;
#pragma unroll
        for (int fj = 0; fj < 4; ++fj) { float v = acc[fi][fj][j]; s += v * v; }
        s += __shfl_xor(s, 1); s += __shfl_xor(s, 2);
        s += __shfl_xor(s, 4); s += __shfl_xor(s, 8);
        if (l15 == 0) {
          int row = tile * EBM + wr * 64 + fi * 16 + lg * 4 + j;
          nu_part[row * 32 + blockIdx.y * 16 + nb * 2 + wc] = s;
        }
      }
    }
  } else if constexpr (EPI == 1) {
    float bv[4];
#pragma unroll
    for (int fj = 0; fj < 4; ++fj)
      bv[fj] = bias[expert * FF + nb * EBN + wc * 64 + fj * 16 + l15];
#pragma unroll
    for (int fi = 0; fi < 4; ++fi)
#pragma unroll
      for (int fj = 0; fj < 4; ++fj)
#pragma unroll
        for (int j = 0; j < 4; ++j) {
          float v = acc[fi][fj][j] + bv[fj];
          float g = 0.5f * v * (1.0f + erff(v * 0.70710678118654752f));  // exact gelu
          int rl = wr * 64 + fi * 16 + lg * 4 + j;
          size_t grow = (size_t)(tile - tile0) * EBM + rl;
          int col = nb * EBN + wc * 64 + fj * 16 + l15;
          hout[grow * FF + col] = f2bf(g);
        }
  } else {
    float bv[4];
#pragma unroll
    for (int fj = 0; fj < 4; ++fj)
      bv[fj] = bias[expert * DD + nb * EBN + wc * 64 + fj * 16 + l15];
#pragma unroll
    for (int fi = 0; fi < 4; ++fi) {
      int rl = wr * 64 + fi * 16 + lg * 4;
#pragma unroll
      for (int j = 0; j < 4; ++j) {
        int tok = tok_s[rl + j];
        float p = p_s[rl + j];
#pragma unroll
        for (int fj = 0; fj < 4; ++fj) {
          float v = (acc[fi][fj][j] + bv[fj]) * p;
          int col = nb * EBN + wc * 64 + fj * 16 + l15;
          atomicAdd(outp + (size_t)tok * DD + col, v);  // exactly 2 adds/elem, commutative -> deterministic
        }
      }
    }
  }
}

// ---------------- host ----------------

extern "C" void kernel_launch(void* const* d_in, const int* in_sizes, int n_in,
                              void* d_out, int out_size, void* d_ws, size_t ws_size,
                              hipStream_t stream) {
  const float* x = (const float*)d_in[0];
  const float* wp = (const float*)d_in[1];
  const float* sim = (const float*)d_in[2];
  const float* temp = (const float*)d_in[3];
  const float* w1 = (const float*)d_in[4];
  const float* b1 = (const float*)d_in[5];
  const float* w2 = (const float*)d_in[6];
  const float* b2 = (const float*)d_in[7];
  float* out = (float*)d_out;

  char* w = (char*)d_ws;
  size_t off = 0;
  auto alloc = [&](size_t sz) {
    char* p = w + off;
    off = (off + sz + 255) & ~(size_t)255;
    return p;
  };
  double* u = (double*)alloc((size_t)NEXP * DD * 8);
  double* u_part = (double*)alloc((size_t)4 * NEXP * DD * 8);
  float* nu_part = (float*)alloc((size_t)NTOK * 32 * 4);
  int* t2e = (int*)alloc((size_t)NTOK * 2 * 4);
  float* t2p = (float*)alloc((size_t)NTOK * 2 * 4);
  int* meta = (int*)alloc(512);
  int* ptok = (int*)alloc((size_t)PAIR_CAP * 4);
  float* pp = (float*)alloc((size_t)PAIR_CAP * 4);
  ushort* xbf = (ushort*)alloc((size_t)NTOK * DD * 2);
  ushort* wpbf = (ushort*)alloc((size_t)DD * DD * 2);
  ushort* w1t = (ushort*)alloc((size_t)NEXP * DD * FF * 2);
  ushort* w2t = (ushort*)alloc((size_t)NEXP * DD * FF * 2);
  size_t havail = (ws_size > off) ? (ws_size - off) : 0;
  int G = (int)(havail / ((size_t)EBM * FF * 2));   // 1MB per tile of h
  if (G > TILES_MAX) G = TILES_MAX;
  if (G >= 8) G &= ~7;                              // multiple of 8 (even + full XCD rounds)
  if (G < 1) G = 1;
  ushort* h = (ushort*)(w + off);

  hipMemsetAsync(d_out, 0, (size_t)out_size * 4, stream);

  k_pre<<<dim3(CONV_BLKS + TR_BLKS + KU_BLKS), 256, 0, stream>>>(
      (const float4*)x, xbf, (const float4*)wp, wpbf, w1, w2, w1t, w2t, wp, sim, u_part);
  k_ured<<<dim3(NEXP * DD / 256), 256, 0, stream>>>(u_part, u);
  gemm_x<0><<<dim3((NTOK / EBM) * (DD / EBN), 2), 256, 0, stream>>>(
      xbf, wpbf, DD, DD, DD / 2, nullptr, nullptr, nullptr, nullptr, nu_part, nullptr,
      nullptr, NTOK / EBM, DD / EBN, 0);
  k_gate<<<dim3(NTOK / 4), 256, 0, stream>>>(x, u, nu_part, temp, t2e, t2p);
  k_count<<<1, 256, 0, stream>>>(t2e, meta, ptok, pp);
  k_scatter<<<dim3(NTOK * 2 / 256), 256, 0, stream>>>(t2e, t2p, meta, ptok, pp);

  for (int t0 = 0; t0 < TILES_MAX; t0 += G) {
    int g = TILES_MAX - t0;
    if (g > G) g = G;
    gemm_x<1><<<dim3(g * (FF / EBN)), 256, 0, stream>>>(
        xbf, w1t, DD, FF, DD, ptok, pp, meta, b1, nullptr, h, nullptr, g, FF / EBN, t0);
    gemm_x<2><<<dim3(g * (DD / EBN)), 256, 0, stream>>>(
        h, w2t, FF, DD, FF, ptok, pp, meta, b2, nullptr, nullptr, out, g, DD / EBN, t0);
  }
}